// Round 1
// baseline (13213.979 us; speedup 1.0000x reference)
//
#include <hip/hip_runtime.h>

#define DEVINL __device__ __forceinline__

// Monotone float->uint key for atomicMax-based float max.
DEVINL unsigned fkey(float f) {
    unsigned b = __float_as_uint(f);
    return (b & 0x80000000u) ? ~b : (b | 0x80000000u);
}
DEVINL float fdecode(unsigned k) {
    unsigned b = (k & 0x80000000u) ? (k ^ 0x80000000u) : ~k;
    return __uint_as_float(b);
}

// x[N,K] @ Wa[K,F] -> oa[N,F]; same x @ Wb -> ob. Thread per (n,f).
__global__ void k_node_lin2(const float* __restrict__ x,
                            const float* __restrict__ Wa,
                            const float* __restrict__ Wb,
                            float* __restrict__ oa, float* __restrict__ ob,
                            int N, int K, int F) {
    int idx = blockIdx.x * blockDim.x + threadIdx.x;
    if (idx >= N * F) return;
    int n = idx / F, f = idx % F;
    const float* xrow = x + (size_t)n * K;
    float aa = 0.f, ab = 0.f;
    for (int k = 0; k < K; ++k) {
        float xv = xrow[k];
        aa += xv * Wa[k * F + f];
        ab += xv * Wb[k * F + f];
    }
    oa[idx] = aa;
    ob[idx] = ab;
}

// Pass 1: per (edge, head) attention logit + segment max via atomicMax on key.
// launch blockDim = 256.
__global__ void k_edge_logits(const int* __restrict__ src, const int* __restrict__ dst,
                              const float* __restrict__ ea,   // [E,4]
                              const float* __restrict__ xl,   // [N,64]
                              const float* __restrict__ xr,   // [N,64]
                              const float* __restrict__ We,   // [4,64]
                              const float* __restrict__ att,  // [4,16] flat 64
                              float* __restrict__ logits,     // [E,4]
                              unsigned* __restrict__ mkey,    // [N,4]
                              int E) {
    __shared__ float sWe[256];
    __shared__ float sAtt[64];
    int tid = threadIdx.x;
    if (tid < 256) sWe[tid] = We[tid];
    if (tid < 64) sAtt[tid] = att[tid];
    __syncthreads();
    int idx = blockIdx.x * blockDim.x + tid;
    if (idx >= E * 4) return;
    int e = idx >> 2, h = idx & 3;
    int s = src[e], d = dst[e];
    float4 a = ((const float4*)ea)[e];
    const float* xls = xl + (size_t)s * 64 + h * 16;
    const float* xrd = xr + (size_t)d * 64 + h * 16;
    const float* w = sWe + h * 16;
    const float* at = sAtt + h * 16;
    float acc = 0.f;
#pragma unroll
    for (int c = 0; c < 16; ++c) {
        float ef = a.x * w[c] + a.y * w[64 + c] + a.z * w[128 + c] + a.w * w[192 + c];
        float v = xls[c] + xrd[c] + ef;
        v = (v >= 0.f) ? v : 0.2f * v;   // LeakyReLU(0.2)
        acc += v * at[c];
    }
    logits[idx] = acc;
    atomicMax(mkey + (size_t)d * 4 + h, fkey(acc));
}

// Pass 2: ex = exp(logit - max); accumulate denominator.
__global__ void k_edge_ex(const int* __restrict__ dst,
                          float* __restrict__ lg,          // in: logits, out: ex
                          const unsigned* __restrict__ mkey,
                          float* __restrict__ denom,       // [N,4]
                          int E) {
    int idx = blockIdx.x * blockDim.x + threadIdx.x;
    if (idx >= E * 4) return;
    int e = idx >> 2, h = idx & 3;
    int d = dst[e];
    float m = fdecode(mkey[(size_t)d * 4 + h]);
    float ex = expf(lg[idx] - m);
    lg[idx] = ex;
    atomicAdd(denom + (size_t)d * 4 + h, ex);
}

// Pass 3: out[dst] += (ex/denom[dst]) * xl[src]
__global__ void k_edge_msg(const int* __restrict__ src, const int* __restrict__ dst,
                           const float* __restrict__ ex,    // [E,4]
                           const float* __restrict__ denom, // [N,4]
                           const float* __restrict__ xl,    // [N,64]
                           float* __restrict__ out,         // [N,64]
                           int E) {
    int idx = blockIdx.x * blockDim.x + threadIdx.x;
    if (idx >= E * 4) return;
    int e = idx >> 2, h = idx & 3;
    int s = src[e], d = dst[e];
    float alpha = ex[idx] / denom[(size_t)d * 4 + h];
    const float* xls = xl + (size_t)s * 64 + h * 16;
    float* od = out + (size_t)d * 64 + h * 16;
#pragma unroll
    for (int c = 0; c < 16; ++c) {
        atomicAdd(od + c, alpha * xls[c]);
    }
}

// y = elu(in + b) elementwise over [N,64]
__global__ void k_bias_elu(const float* __restrict__ in, const float* __restrict__ b,
                           float* __restrict__ out, int NF) {
    int idx = blockIdx.x * blockDim.x + threadIdx.x;
    if (idx >= NF) return;
    int f = idx & 63;
    float v = in[idx] + b[f];
    out[idx] = (v > 0.f) ? v : expm1f(v);
}

// pool[batch[n]] += out2[n] + b2 ; cnt[batch[n]] += 1
__global__ void k_pool(const float* __restrict__ out2, const float* __restrict__ b2,
                       const int* __restrict__ batch,
                       float* __restrict__ pool, float* __restrict__ cnt, int N) {
    int idx = blockIdx.x * blockDim.x + threadIdx.x;
    if (idx >= N * 64) return;
    int n = idx >> 6, f = idx & 63;
    float v = out2[idx] + b2[f];
    int g = batch[n];
    atomicAdd(pool + (size_t)g * 64 + f, v);
    if (f == 0) atomicAdd(cnt + g, 1.0f);
}

// One block (64 threads) per graph: mean, 3 MLP heads.
__global__ void k_head(const float* __restrict__ pool, const float* __restrict__ cnt,
                       const float* __restrict__ Wg1, const float* __restrict__ bg1,
                       const float* __restrict__ Wg2, const float* __restrict__ bg2,
                       const float* __restrict__ Wp, const float* __restrict__ bp,
                       const float* __restrict__ Wc1, const float* __restrict__ bc1,
                       const float* __restrict__ Wc2, const float* __restrict__ bc2,
                       float* __restrict__ out) {
    int g = blockIdx.x, f = threadIdx.x;
    __shared__ float sg[64];
    __shared__ float sh[64];
    float inv = 1.f / fmaxf(cnt[g], 1.f);
    sg[f] = pool[(size_t)g * 64 + f] * inv;
    __syncthreads();
    // gmm hidden
    float acc = bg1[f];
    for (int k = 0; k < 64; ++k) acc += sg[k] * Wg1[k * 64 + f];
    sh[f] = fmaxf(acc, 0.f);
    __syncthreads();
    if (f < 15) {
        float o = bg2[f];
        for (int k = 0; k < 64; ++k) o += sh[k] * Wg2[k * 15 + f];
        out[(size_t)g * 15 + f] = o;
    }
    if (f < 10) {
        float o = bp[f];
        for (int k = 0; k < 64; ++k) o += sg[k] * Wp[k * 10 + f];
        out[960 + (size_t)g * 10 + f] = o;
    }
    __syncthreads();
    // critic hidden (reuse sh)
    float acc2 = bc1[f];
    for (int k = 0; k < 64; ++k) acc2 += sg[k] * Wc1[k * 64 + f];
    sh[f] = fmaxf(acc2, 0.f);
    __syncthreads();
    if (f == 0) {
        float v = bc2[0];
        for (int k = 0; k < 64; ++k) v += sh[k] * Wc2[k];
        out[1600 + g] = v;
    }
}

extern "C" void kernel_launch(void* const* d_in, const int* in_sizes, int n_in,
                              void* d_out, int out_size, void* d_ws, size_t ws_size,
                              hipStream_t stream) {
    const float* x     = (const float*)d_in[0];
    const int*   ei    = (const int*)d_in[1];
    const float* ea    = (const float*)d_in[2];
    const int*   batch = (const int*)d_in[3];
    const float* Wl1 = (const float*)d_in[4];
    const float* Wr1 = (const float*)d_in[5];
    const float* We1 = (const float*)d_in[6];
    const float* att1 = (const float*)d_in[7];
    const float* b1  = (const float*)d_in[8];
    const float* Wl2 = (const float*)d_in[9];
    const float* Wr2 = (const float*)d_in[10];
    const float* We2 = (const float*)d_in[11];
    const float* att2 = (const float*)d_in[12];
    const float* b2  = (const float*)d_in[13];
    const float* Wg1 = (const float*)d_in[14];
    const float* bg1 = (const float*)d_in[15];
    const float* Wg2 = (const float*)d_in[16];
    const float* bg2 = (const float*)d_in[17];
    const float* Wp  = (const float*)d_in[18];
    const float* bp  = (const float*)d_in[19];
    const float* Wc1 = (const float*)d_in[20];
    const float* bc1 = (const float*)d_in[21];
    const float* Wc2 = (const float*)d_in[22];
    const float* bc2 = (const float*)d_in[23];

    const int N = in_sizes[0] / 16;       // 100000
    const int E = in_sizes[2] / 4;        // 1600000
    const int* src = ei;
    const int* dst = ei + E;

    // workspace layout (floats)
    float* ws = (float*)d_ws;
    size_t NF = (size_t)N * 64;
    float* A  = ws;             // xl1, later xr2
    float* B  = A + NF;         // xr1, later xl2
    float* C  = B + NF;         // out1/y1, later out2
    float* L  = C + NF;         // logits / ex  [E,4]
    unsigned* MK = (unsigned*)(L + (size_t)E * 4);  // [N,4]
    float* DN = (float*)(MK + (size_t)N * 4);       // [N,4]
    float* PL = DN + (size_t)N * 4;                 // [64,64]
    float* CT = PL + 64 * 64;                       // [64]

    dim3 blk(256);
    int gNF = (int)((NF + 255) / 256);
    int gE4 = (E * 4 + 255) / 256;

    // ---- Layer 1 ----
    k_node_lin2<<<gNF, blk, 0, stream>>>(x, Wl1, Wr1, A, B, N, 16, 64);
    hipMemsetAsync(MK, 0, (size_t)N * 4 * sizeof(unsigned), stream);
    hipMemsetAsync(DN, 0, (size_t)N * 4 * sizeof(float), stream);
    hipMemsetAsync(C, 0, NF * sizeof(float), stream);
    k_edge_logits<<<gE4, blk, 0, stream>>>(src, dst, ea, A, B, We1, att1, L, MK, E);
    k_edge_ex<<<gE4, blk, 0, stream>>>(dst, L, MK, DN, E);
    k_edge_msg<<<gE4, blk, 0, stream>>>(src, dst, L, DN, A, C, E);
    k_bias_elu<<<gNF, blk, 0, stream>>>(C, b1, C, (int)NF);

    // ---- Layer 2 ----  (xl2 -> B, xr2 -> A; both free now)
    k_node_lin2<<<gNF, blk, 0, stream>>>(C, Wl2, Wr2, B, A, N, 64, 64);
    hipMemsetAsync(MK, 0, (size_t)N * 4 * sizeof(unsigned), stream);
    hipMemsetAsync(DN, 0, (size_t)N * 4 * sizeof(float), stream);
    hipMemsetAsync(C, 0, NF * sizeof(float), stream);
    k_edge_logits<<<gE4, blk, 0, stream>>>(src, dst, ea, B, A, We2, att2, L, MK, E);
    k_edge_ex<<<gE4, blk, 0, stream>>>(dst, L, MK, DN, E);
    k_edge_msg<<<gE4, blk, 0, stream>>>(src, dst, L, DN, B, C, E);

    // ---- Pool + heads ----
    hipMemsetAsync(PL, 0, (64 * 64 + 64) * sizeof(float), stream);
    k_pool<<<gNF, blk, 0, stream>>>(C, b2, batch, PL, CT, N);
    k_head<<<64, 64, 0, stream>>>(PL, CT, Wg1, bg1, Wg2, bg2, Wp, bp,
                                  Wc1, bc1, Wc2, bc2, (float*)d_out);
}

// Round 2
// 1795.281 us; speedup vs baseline: 7.3604x; 7.3604x over previous
//
#include <hip/hip_runtime.h>

// x[N,K] @ Wa[K,F] -> oa[N,F]; same x @ Wb -> ob. Thread per (n,f).
__global__ void k_node_lin2(const float* __restrict__ x,
                            const float* __restrict__ Wa,
                            const float* __restrict__ Wb,
                            float* __restrict__ oa, float* __restrict__ ob,
                            int N, int K, int F) {
    int idx = blockIdx.x * blockDim.x + threadIdx.x;
    if (idx >= N * F) return;
    int n = idx / F, f = idx % F;
    const float* xrow = x + (size_t)n * K;
    float aa = 0.f, ab = 0.f;
    for (int k = 0; k < K; ++k) {
        float xv = xrow[k];
        aa += xv * Wa[k * F + f];
        ab += xv * Wb[k * F + f];
    }
    oa[idx] = aa;
    ob[idx] = ab;
}

// ---- CSR build ----
__global__ void k_deg(const int* __restrict__ dst, int* __restrict__ deg, int E) {
    int e = blockIdx.x * blockDim.x + threadIdx.x;
    if (e < E) atomicAdd(&deg[dst[e]], 1);
}

// per-block (1024 elems) inclusive scan; block total -> bsum
__global__ void k_scan1(const int* __restrict__ deg, int* __restrict__ spart,
                        int* __restrict__ bsum, int N) {
    __shared__ int sh[256];
    int base = blockIdx.x * 1024;
    int t = threadIdx.x;
    int v[4]; int sum = 0;
#pragma unroll
    for (int i = 0; i < 4; ++i) {
        int idx = base + t * 4 + i;
        v[i] = (idx < N) ? deg[idx] : 0;
        sum += v[i];
    }
    sh[t] = sum;
    __syncthreads();
    for (int off = 1; off < 256; off <<= 1) {
        int x = (t >= off) ? sh[t - off] : 0;
        __syncthreads();
        sh[t] += x;
        __syncthreads();
    }
    int run = (t > 0) ? sh[t - 1] : 0;
#pragma unroll
    for (int i = 0; i < 4; ++i) {
        run += v[i];
        int idx = base + t * 4 + i;
        if (idx < N) spart[idx] = run;
    }
    if (t == 255) bsum[blockIdx.x] = sh[255];
}

// exclusive scan of block sums (single block, nb <= 128)
__global__ void k_scan2(int* __restrict__ bsum, int nb) {
    __shared__ int sh[128];
    int t = threadIdx.x;
    sh[t] = (t < nb) ? bsum[t] : 0;
    __syncthreads();
    for (int off = 1; off < 128; off <<= 1) {
        int x = (t >= off) ? sh[t - off] : 0;
        __syncthreads();
        sh[t] += x;
        __syncthreads();
    }
    if (t < nb) bsum[t] = (t > 0) ? sh[t - 1] : 0;
}

// rowptr[i+1] = spart[i] + bsum[i/1024]; rowptr[0]=0
__global__ void k_scan3(const int* __restrict__ spart, const int* __restrict__ bsum,
                        int* __restrict__ rowptr, int N) {
    int i = blockIdx.x * blockDim.x + threadIdx.x;
    if (i < N) rowptr[i + 1] = spart[i] + bsum[i >> 10];
    if (i == 0) rowptr[0] = 0;
}

__global__ void k_scatter(const int* __restrict__ src, const int* __restrict__ dst,
                          const int* __restrict__ rowptr, int* __restrict__ fill,
                          int* __restrict__ csr_src, int* __restrict__ csr_eid, int E) {
    int e = blockIdx.x * blockDim.x + threadIdx.x;
    if (e >= E) return;
    int d = dst[e];
    int pos = rowptr[d] + atomicAdd(&fill[d], 1);
    csr_src[pos] = src[e];
    csr_eid[pos] = e;
}

// Attention logits per (edge, head). blockDim = 256.
__global__ void k_edge_logits(const int* __restrict__ src, const int* __restrict__ dst,
                              const float* __restrict__ ea,   // [E,4]
                              const float* __restrict__ xl,   // [N,64]
                              const float* __restrict__ xr,   // [N,64]
                              const float* __restrict__ We,   // [4,64]
                              const float* __restrict__ att,  // [4,16] flat 64
                              float* __restrict__ logits,     // [E,4]
                              int E) {
    __shared__ float sWe[256];
    __shared__ float sAtt[64];
    int tid = threadIdx.x;
    sWe[tid] = We[tid];
    if (tid < 64) sAtt[tid] = att[tid];
    __syncthreads();
    int idx = blockIdx.x * blockDim.x + tid;
    if (idx >= E * 4) return;
    int e = idx >> 2, h = idx & 3;
    int s = src[e], d = dst[e];
    float4 a = ((const float4*)ea)[e];
    const float* xls = xl + (size_t)s * 64 + h * 16;
    const float* xrd = xr + (size_t)d * 64 + h * 16;
    const float* w = sWe + h * 16;
    const float* at = sAtt + h * 16;
    float acc = 0.f;
#pragma unroll
    for (int c = 0; c < 16; ++c) {
        float ef = a.x * w[c] + a.y * w[64 + c] + a.z * w[128 + c] + a.w * w[192 + c];
        float v = xls[c] + xrd[c] + ef;
        v = (v >= 0.f) ? v : 0.2f * v;   // LeakyReLU(0.2)
        acc += v * at[c];
    }
    logits[idx] = acc;
}

// Node-parallel softmax + aggregate. 64 threads per node, 4 nodes per block.
// out[n,t] = sum_j softmax_j(logit[j,h]) * xl[src_j, t]  + bias[t]  (+ optional ELU)
__global__ void k_node_agg(const int* __restrict__ rowptr,
                           const int* __restrict__ csr_src,
                           const int* __restrict__ csr_eid,
                           const float* __restrict__ L,    // [E,4]
                           const float* __restrict__ xl,   // [N,64]
                           const float* __restrict__ bias, // [64]
                           float* __restrict__ out,        // [N,64]
                           int N, int elu) {
    int t = threadIdx.x & 63;
    int n = blockIdx.x * 4 + (threadIdx.x >> 6);
    if (n >= N) return;
    int h = t >> 4;
    int beg = rowptr[n], end = rowptr[n + 1];
    float maxv = -INFINITY;
    for (int j = beg; j < end; ++j) {
        maxv = fmaxf(maxv, L[(size_t)csr_eid[j] * 4 + h]);
    }
    float denom = 0.f, acc = 0.f;
    for (int j = beg; j < end; ++j) {
        float ex = expf(L[(size_t)csr_eid[j] * 4 + h] - maxv);
        denom += ex;
        acc += ex * xl[(size_t)csr_src[j] * 64 + t];
    }
    float val = (end > beg) ? (acc / denom) : 0.f;
    val += bias[t];
    if (elu) val = (val > 0.f) ? val : expm1f(val);
    out[(size_t)n * 64 + t] = val;
}

// pool[batch[n]] += y2[n] ; cnt[batch[n]] += 1   (bias already folded)
__global__ void k_pool(const float* __restrict__ y2,
                       const int* __restrict__ batch,
                       float* __restrict__ pool, float* __restrict__ cnt, int N) {
    int idx = blockIdx.x * blockDim.x + threadIdx.x;
    if (idx >= N * 64) return;
    int n = idx >> 6, f = idx & 63;
    int g = batch[n];
    atomicAdd(pool + (size_t)g * 64 + f, y2[idx]);
    if (f == 0) atomicAdd(cnt + g, 1.0f);
}

// One block (64 threads) per graph: mean, 3 MLP heads.
__global__ void k_head(const float* __restrict__ pool, const float* __restrict__ cnt,
                       const float* __restrict__ Wg1, const float* __restrict__ bg1,
                       const float* __restrict__ Wg2, const float* __restrict__ bg2,
                       const float* __restrict__ Wp, const float* __restrict__ bp,
                       const float* __restrict__ Wc1, const float* __restrict__ bc1,
                       const float* __restrict__ Wc2, const float* __restrict__ bc2,
                       float* __restrict__ out) {
    int g = blockIdx.x, f = threadIdx.x;
    __shared__ float sg[64];
    __shared__ float sh[64];
    float inv = 1.f / fmaxf(cnt[g], 1.f);
    sg[f] = pool[(size_t)g * 64 + f] * inv;
    __syncthreads();
    float acc = bg1[f];
    for (int k = 0; k < 64; ++k) acc += sg[k] * Wg1[k * 64 + f];
    sh[f] = fmaxf(acc, 0.f);
    __syncthreads();
    if (f < 15) {
        float o = bg2[f];
        for (int k = 0; k < 64; ++k) o += sh[k] * Wg2[k * 15 + f];
        out[(size_t)g * 15 + f] = o;
    }
    if (f < 10) {
        float o = bp[f];
        for (int k = 0; k < 64; ++k) o += sg[k] * Wp[k * 10 + f];
        out[960 + (size_t)g * 10 + f] = o;
    }
    __syncthreads();
    float acc2 = bc1[f];
    for (int k = 0; k < 64; ++k) acc2 += sg[k] * Wc1[k * 64 + f];
    sh[f] = fmaxf(acc2, 0.f);
    __syncthreads();
    if (f == 0) {
        float v = bc2[0];
        for (int k = 0; k < 64; ++k) v += sh[k] * Wc2[k];
        out[1600 + g] = v;
    }
}

extern "C" void kernel_launch(void* const* d_in, const int* in_sizes, int n_in,
                              void* d_out, int out_size, void* d_ws, size_t ws_size,
                              hipStream_t stream) {
    const float* x     = (const float*)d_in[0];
    const int*   ei    = (const int*)d_in[1];
    const float* ea    = (const float*)d_in[2];
    const int*   batch = (const int*)d_in[3];
    const float* Wl1 = (const float*)d_in[4];
    const float* Wr1 = (const float*)d_in[5];
    const float* We1 = (const float*)d_in[6];
    const float* att1 = (const float*)d_in[7];
    const float* b1  = (const float*)d_in[8];
    const float* Wl2 = (const float*)d_in[9];
    const float* Wr2 = (const float*)d_in[10];
    const float* We2 = (const float*)d_in[11];
    const float* att2 = (const float*)d_in[12];
    const float* b2  = (const float*)d_in[13];
    const float* Wg1 = (const float*)d_in[14];
    const float* bg1 = (const float*)d_in[15];
    const float* Wg2 = (const float*)d_in[16];
    const float* bg2 = (const float*)d_in[17];
    const float* Wp  = (const float*)d_in[18];
    const float* bp  = (const float*)d_in[19];
    const float* Wc1 = (const float*)d_in[20];
    const float* bc1 = (const float*)d_in[21];
    const float* Wc2 = (const float*)d_in[22];
    const float* bc2 = (const float*)d_in[23];

    const int N = in_sizes[0] / 16;       // 100000
    const int E = in_sizes[2] / 4;        // 1600000
    const int* src = ei;
    const int* dst = ei + E;

    // workspace layout
    float* ws = (float*)d_ws;
    size_t NF = (size_t)N * 64;
    float* A  = ws;                       // xl1, later xr2
    float* B  = A + NF;                   // xr1, later xl2
    float* C  = B + NF;                   // y1, later y2
    float* L  = C + NF;                   // logits [E,4]
    int* csr_src = (int*)(L + (size_t)E * 4);
    int* csr_eid = csr_src + E;
    int* rowptr  = csr_eid + E;           // N+1
    int* deg     = rowptr + (N + 1);      // N (reused as fill)
    int* spart   = deg + N;               // N
    int* bsum    = spart + N;             // 128
    float* PL    = (float*)(bsum + 128);  // [64,64]
    float* CT    = PL + 64 * 64;          // [64]

    dim3 blk(256);
    int gNF = (int)((NF + 255) / 256);
    int gE4 = (E * 4 + 255) / 256;
    int gE  = (E + 255) / 256;
    int gN  = (N + 255) / 256;
    int nb1 = (N + 1023) / 1024;

    // ---- CSR build (shared by both layers) ----
    hipMemsetAsync(deg, 0, (size_t)N * sizeof(int), stream);
    k_deg<<<gE, blk, 0, stream>>>(dst, deg, E);
    k_scan1<<<nb1, blk, 0, stream>>>(deg, spart, bsum, N);
    k_scan2<<<1, 128, 0, stream>>>(bsum, nb1);
    k_scan3<<<gN, blk, 0, stream>>>(spart, bsum, rowptr, N);
    hipMemsetAsync(deg, 0, (size_t)N * sizeof(int), stream);  // reuse as fill
    k_scatter<<<gE, blk, 0, stream>>>(src, dst, rowptr, deg, csr_src, csr_eid, E);

    // ---- Layer 1 ----
    k_node_lin2<<<gNF, blk, 0, stream>>>(x, Wl1, Wr1, A, B, N, 16, 64);
    k_edge_logits<<<gE4, blk, 0, stream>>>(src, dst, ea, A, B, We1, att1, L, E);
    k_node_agg<<<(N + 3) / 4, blk, 0, stream>>>(rowptr, csr_src, csr_eid, L, A, b1, C, N, 1);

    // ---- Layer 2 ---- (xl2 -> B, xr2 -> A)
    k_node_lin2<<<gNF, blk, 0, stream>>>(C, Wl2, Wr2, B, A, N, 64, 64);
    k_edge_logits<<<gE4, blk, 0, stream>>>(src, dst, ea, B, A, We2, att2, L, E);
    k_node_agg<<<(N + 3) / 4, blk, 0, stream>>>(rowptr, csr_src, csr_eid, L, B, b2, C, N, 0);

    // ---- Pool + heads ----
    hipMemsetAsync(PL, 0, (64 * 64 + 64) * sizeof(float), stream);
    k_pool<<<gNF, blk, 0, stream>>>(C, batch, PL, CT, N);
    k_head<<<64, 64, 0, stream>>>(PL, CT, Wg1, bg1, Wg2, bg2, Wp, bp,
                                  Wc1, bc1, Wc2, bc2, (float*)d_out);
}

// Round 3
// 1197.409 us; speedup vs baseline: 11.0355x; 1.4993x over previous
//
#include <hip/hip_runtime.h>

// x[N,K] @ Wa[K,F] -> oa[N,F]; same x @ Wb -> ob. Thread per (n,f).
__global__ void k_node_lin2(const float* __restrict__ x,
                            const float* __restrict__ Wa,
                            const float* __restrict__ Wb,
                            float* __restrict__ oa, float* __restrict__ ob,
                            int N, int K, int F) {
    int idx = blockIdx.x * blockDim.x + threadIdx.x;
    if (idx >= N * F) return;
    int n = idx / F, f = idx % F;
    const float* xrow = x + (size_t)n * K;
    float aa = 0.f, ab = 0.f;
    for (int k = 0; k < K; ++k) {
        float xv = xrow[k];
        aa += xv * Wa[k * F + f];
        ab += xv * Wb[k * F + f];
    }
    oa[idx] = aa;
    ob[idx] = ab;
}

// ---- CSR build ----
__global__ void k_deg(const int* __restrict__ dst, int* __restrict__ deg, int E) {
    int e = blockIdx.x * blockDim.x + threadIdx.x;
    if (e < E) atomicAdd(&deg[dst[e]], 1);
}

__global__ void k_scan1(const int* __restrict__ deg, int* __restrict__ spart,
                        int* __restrict__ bsum, int N) {
    __shared__ int sh[256];
    int base = blockIdx.x * 1024;
    int t = threadIdx.x;
    int v[4]; int sum = 0;
#pragma unroll
    for (int i = 0; i < 4; ++i) {
        int idx = base + t * 4 + i;
        v[i] = (idx < N) ? deg[idx] : 0;
        sum += v[i];
    }
    sh[t] = sum;
    __syncthreads();
    for (int off = 1; off < 256; off <<= 1) {
        int x = (t >= off) ? sh[t - off] : 0;
        __syncthreads();
        sh[t] += x;
        __syncthreads();
    }
    int run = (t > 0) ? sh[t - 1] : 0;
#pragma unroll
    for (int i = 0; i < 4; ++i) {
        run += v[i];
        int idx = base + t * 4 + i;
        if (idx < N) spart[idx] = run;
    }
    if (t == 255) bsum[blockIdx.x] = sh[255];
}

__global__ void k_scan2(int* __restrict__ bsum, int nb) {
    __shared__ int sh[128];
    int t = threadIdx.x;
    sh[t] = (t < nb) ? bsum[t] : 0;
    __syncthreads();
    for (int off = 1; off < 128; off <<= 1) {
        int x = (t >= off) ? sh[t - off] : 0;
        __syncthreads();
        sh[t] += x;
        __syncthreads();
    }
    if (t < nb) bsum[t] = (t > 0) ? sh[t - 1] : 0;
}

__global__ void k_scan3(const int* __restrict__ spart, const int* __restrict__ bsum,
                        int* __restrict__ rowptr, int N) {
    int i = blockIdx.x * blockDim.x + threadIdx.x;
    if (i < N) rowptr[i + 1] = spart[i] + bsum[i >> 10];
    if (i == 0) rowptr[0] = 0;
}

__global__ void k_scatter(const int* __restrict__ src, const int* __restrict__ dst,
                          const int* __restrict__ rowptr, int* __restrict__ fill,
                          int* __restrict__ csr_src, int* __restrict__ csr_eid, int E) {
    int e = blockIdx.x * blockDim.x + threadIdx.x;
    if (e >= E) return;
    int d = dst[e];
    int pos = rowptr[d] + atomicAdd(&fill[d], 1);
    csr_src[pos] = src[e];
    csr_eid[pos] = e;
}

// Attention logits per (edge, head). blockDim = 256.
__global__ void k_edge_logits(const int* __restrict__ src, const int* __restrict__ dst,
                              const float* __restrict__ ea,   // [E,4]
                              const float* __restrict__ xl,   // [N,64]
                              const float* __restrict__ xr,   // [N,64]
                              const float* __restrict__ We,   // [4,64]
                              const float* __restrict__ att,  // [4,16] flat 64
                              float* __restrict__ logits,     // [E,4]
                              int E) {
    __shared__ float sWe[256];
    __shared__ float sAtt[64];
    int tid = threadIdx.x;
    sWe[tid] = We[tid];
    if (tid < 64) sAtt[tid] = att[tid];
    __syncthreads();
    int idx = blockIdx.x * blockDim.x + tid;
    if (idx >= E * 4) return;
    int e = idx >> 2, h = idx & 3;
    int s = src[e], d = dst[e];
    float4 a = ((const float4*)ea)[e];
    const float* xls = xl + (size_t)s * 64 + h * 16;
    const float* xrd = xr + (size_t)d * 64 + h * 16;
    const float* w = sWe + h * 16;
    const float* at = sAtt + h * 16;
    float acc = 0.f;
#pragma unroll
    for (int c = 0; c < 16; ++c) {
        float ef = a.x * w[c] + a.y * w[64 + c] + a.z * w[128 + c] + a.w * w[192 + c];
        float v = xls[c] + xrd[c] + ef;
        v = (v >= 0.f) ? v : 0.2f * v;   // LeakyReLU(0.2)
        acc += v * at[c];
    }
    logits[idx] = acc;
}

// Node-parallel softmax + aggregate. 64 threads per node, 4 nodes per block.
__global__ void k_node_agg(const int* __restrict__ rowptr,
                           const int* __restrict__ csr_src,
                           const int* __restrict__ csr_eid,
                           const float* __restrict__ L,    // [E,4]
                           const float* __restrict__ xl,   // [N,64]
                           const float* __restrict__ bias, // [64]
                           float* __restrict__ out,        // [N,64]
                           int N, int elu) {
    int t = threadIdx.x & 63;
    int n = blockIdx.x * 4 + (threadIdx.x >> 6);
    if (n >= N) return;
    int h = t >> 4;
    int beg = rowptr[n], end = rowptr[n + 1];
    float maxv = -INFINITY;
    for (int j = beg; j < end; ++j) {
        maxv = fmaxf(maxv, L[(size_t)csr_eid[j] * 4 + h]);
    }
    float denom = 0.f, acc = 0.f;
    for (int j = beg; j < end; ++j) {
        float ex = expf(L[(size_t)csr_eid[j] * 4 + h] - maxv);
        denom += ex;
        acc += ex * xl[(size_t)csr_src[j] * 64 + t];
    }
    float val = (end > beg) ? (acc / denom) : 0.f;
    val += bias[t];
    if (elu) val = (val > 0.f) ? val : expm1f(val);
    out[(size_t)n * 64 + t] = val;
}

// Run-length accumulating pool: block owns 256 contiguous nodes; thread t owns
// feature t&63, walks nodes with stride 4, flushes one atomicAdd per graph-run.
__global__ void k_pool(const float* __restrict__ y2,
                       const int* __restrict__ batch,
                       float* __restrict__ pool, float* __restrict__ cnt, int N) {
    const int CH = 256;
    int f = threadIdx.x & 63;
    int lane = threadIdx.x >> 6;          // 0..3
    int base = blockIdx.x * CH;
    int curg = -1;
    float acc = 0.f;
    float c = 0.f;
    for (int n = base + lane; n < base + CH && n < N; n += 4) {
        int g = batch[n];
        if (g != curg) {
            if (curg >= 0) {
                atomicAdd(pool + (size_t)curg * 64 + f, acc);
                if (f == 0) atomicAdd(cnt + curg, c);
            }
            curg = g; acc = 0.f; c = 0.f;
        }
        acc += y2[(size_t)n * 64 + f];
        c += 1.f;
    }
    if (curg >= 0) {
        atomicAdd(pool + (size_t)curg * 64 + f, acc);
        if (f == 0) atomicAdd(cnt + curg, c);
    }
}

// One block (64 threads) per graph: mean, 3 MLP heads.
__global__ void k_head(const float* __restrict__ pool, const float* __restrict__ cnt,
                       const float* __restrict__ Wg1, const float* __restrict__ bg1,
                       const float* __restrict__ Wg2, const float* __restrict__ bg2,
                       const float* __restrict__ Wp, const float* __restrict__ bp,
                       const float* __restrict__ Wc1, const float* __restrict__ bc1,
                       const float* __restrict__ Wc2, const float* __restrict__ bc2,
                       float* __restrict__ out) {
    int g = blockIdx.x, f = threadIdx.x;
    __shared__ float sg[64];
    __shared__ float sh[64];
    float inv = 1.f / fmaxf(cnt[g], 1.f);
    sg[f] = pool[(size_t)g * 64 + f] * inv;
    __syncthreads();
    float acc = bg1[f];
    for (int k = 0; k < 64; ++k) acc += sg[k] * Wg1[k * 64 + f];
    sh[f] = fmaxf(acc, 0.f);
    __syncthreads();
    if (f < 15) {
        float o = bg2[f];
        for (int k = 0; k < 64; ++k) o += sh[k] * Wg2[k * 15 + f];
        out[(size_t)g * 15 + f] = o;
    }
    if (f < 10) {
        float o = bp[f];
        for (int k = 0; k < 64; ++k) o += sg[k] * Wp[k * 10 + f];
        out[960 + (size_t)g * 10 + f] = o;
    }
    __syncthreads();
    float acc2 = bc1[f];
    for (int k = 0; k < 64; ++k) acc2 += sg[k] * Wc1[k * 64 + f];
    sh[f] = fmaxf(acc2, 0.f);
    __syncthreads();
    if (f == 0) {
        float v = bc2[0];
        for (int k = 0; k < 64; ++k) v += sh[k] * Wc2[k];
        out[1600 + g] = v;
    }
}

extern "C" void kernel_launch(void* const* d_in, const int* in_sizes, int n_in,
                              void* d_out, int out_size, void* d_ws, size_t ws_size,
                              hipStream_t stream) {
    const float* x     = (const float*)d_in[0];
    const int*   ei    = (const int*)d_in[1];
    const float* ea    = (const float*)d_in[2];
    const int*   batch = (const int*)d_in[3];
    const float* Wl1 = (const float*)d_in[4];
    const float* Wr1 = (const float*)d_in[5];
    const float* We1 = (const float*)d_in[6];
    const float* att1 = (const float*)d_in[7];
    const float* b1  = (const float*)d_in[8];
    const float* Wl2 = (const float*)d_in[9];
    const float* Wr2 = (const float*)d_in[10];
    const float* We2 = (const float*)d_in[11];
    const float* att2 = (const float*)d_in[12];
    const float* b2  = (const float*)d_in[13];
    const float* Wg1 = (const float*)d_in[14];
    const float* bg1 = (const float*)d_in[15];
    const float* Wg2 = (const float*)d_in[16];
    const float* bg2 = (const float*)d_in[17];
    const float* Wp  = (const float*)d_in[18];
    const float* bp  = (const float*)d_in[19];
    const float* Wc1 = (const float*)d_in[20];
    const float* bc1 = (const float*)d_in[21];
    const float* Wc2 = (const float*)d_in[22];
    const float* bc2 = (const float*)d_in[23];

    const int N = in_sizes[0] / 16;       // 100000
    const int E = in_sizes[2] / 4;        // 1600000
    const int* src = ei;
    const int* dst = ei + E;

    // workspace layout
    float* ws = (float*)d_ws;
    size_t NF = (size_t)N * 64;
    float* A  = ws;                       // xl1, later xr2
    float* B  = A + NF;                   // xr1, later xl2
    float* C  = B + NF;                   // y1, later y2
    float* L  = C + NF;                   // logits [E,4]
    int* csr_src = (int*)(L + (size_t)E * 4);
    int* csr_eid = csr_src + E;
    int* rowptr  = csr_eid + E;           // N+1
    int* deg     = rowptr + (N + 1);      // N (reused as fill)
    int* spart   = deg + N;               // N
    int* bsum    = spart + N;             // 128
    float* PL    = (float*)(bsum + 128);  // [64,64]
    float* CT    = PL + 64 * 64;          // [64]

    dim3 blk(256);
    int gNF = (int)((NF + 255) / 256);
    int gE4 = (E * 4 + 255) / 256;
    int gE  = (E + 255) / 256;
    int gN  = (N + 255) / 256;
    int nb1 = (N + 1023) / 1024;

    // ---- CSR build (shared by both layers) ----
    hipMemsetAsync(deg, 0, (size_t)N * sizeof(int), stream);
    k_deg<<<gE, blk, 0, stream>>>(dst, deg, E);
    k_scan1<<<nb1, blk, 0, stream>>>(deg, spart, bsum, N);
    k_scan2<<<1, 128, 0, stream>>>(bsum, nb1);
    k_scan3<<<gN, blk, 0, stream>>>(spart, bsum, rowptr, N);
    hipMemsetAsync(deg, 0, (size_t)N * sizeof(int), stream);  // reuse as fill
    k_scatter<<<gE, blk, 0, stream>>>(src, dst, rowptr, deg, csr_src, csr_eid, E);

    // ---- Layer 1 ----
    k_node_lin2<<<gNF, blk, 0, stream>>>(x, Wl1, Wr1, A, B, N, 16, 64);
    k_edge_logits<<<gE4, blk, 0, stream>>>(src, dst, ea, A, B, We1, att1, L, E);
    k_node_agg<<<(N + 3) / 4, blk, 0, stream>>>(rowptr, csr_src, csr_eid, L, A, b1, C, N, 1);

    // ---- Layer 2 ---- (xl2 -> B, xr2 -> A)
    k_node_lin2<<<gNF, blk, 0, stream>>>(C, Wl2, Wr2, B, A, N, 64, 64);
    k_edge_logits<<<gE4, blk, 0, stream>>>(src, dst, ea, B, A, We2, att2, L, E);
    k_node_agg<<<(N + 3) / 4, blk, 0, stream>>>(rowptr, csr_src, csr_eid, L, B, b2, C, N, 0);

    // ---- Pool + heads ----
    hipMemsetAsync(PL, 0, (64 * 64 + 64) * sizeof(float), stream);
    k_pool<<<(N + 255) / 256, blk, 0, stream>>>(C, batch, PL, CT, N);
    k_head<<<64, 64, 0, stream>>>(PL, CT, Wg1, bg1, Wg2, bg2, Wp, bp,
                                  Wc1, bc1, Wc2, bc2, (float*)d_out);
}

// Round 4
// 844.941 us; speedup vs baseline: 15.6389x; 1.4172x over previous
//
#include <hip/hip_runtime.h>

// x[N,K] @ Wa[K,F] -> oa[N,F]; same x @ Wb -> ob. Thread per (n,f).
__global__ void k_node_lin2(const float* __restrict__ x,
                            const float* __restrict__ Wa,
                            const float* __restrict__ Wb,
                            float* __restrict__ oa, float* __restrict__ ob,
                            int N, int K, int F) {
    int idx = blockIdx.x * blockDim.x + threadIdx.x;
    if (idx >= N * F) return;
    int n = idx / F, f = idx % F;
    const float* xrow = x + (size_t)n * K;
    float aa = 0.f, ab = 0.f;
    for (int k = 0; k < K; ++k) {
        float xv = xrow[k];
        aa += xv * Wa[k * F + f];
        ab += xv * Wb[k * F + f];
    }
    oa[idx] = aa;
    ob[idx] = ab;
}

// ---- CSR build ----
__global__ void k_deg(const int* __restrict__ dst, int* __restrict__ deg, int E) {
    int e = blockIdx.x * blockDim.x + threadIdx.x;
    if (e < E) atomicAdd(&deg[dst[e]], 1);
}

__global__ void k_scan1(const int* __restrict__ deg, int* __restrict__ spart,
                        int* __restrict__ bsum, int N) {
    __shared__ int sh[256];
    int base = blockIdx.x * 1024;
    int t = threadIdx.x;
    int v[4]; int sum = 0;
#pragma unroll
    for (int i = 0; i < 4; ++i) {
        int idx = base + t * 4 + i;
        v[i] = (idx < N) ? deg[idx] : 0;
        sum += v[i];
    }
    sh[t] = sum;
    __syncthreads();
    for (int off = 1; off < 256; off <<= 1) {
        int x = (t >= off) ? sh[t - off] : 0;
        __syncthreads();
        sh[t] += x;
        __syncthreads();
    }
    int run = (t > 0) ? sh[t - 1] : 0;
#pragma unroll
    for (int i = 0; i < 4; ++i) {
        run += v[i];
        int idx = base + t * 4 + i;
        if (idx < N) spart[idx] = run;
    }
    if (t == 255) bsum[blockIdx.x] = sh[255];
}

__global__ void k_scan2(int* __restrict__ bsum, int nb) {
    __shared__ int sh[128];
    int t = threadIdx.x;
    sh[t] = (t < nb) ? bsum[t] : 0;
    __syncthreads();
    for (int off = 1; off < 128; off <<= 1) {
        int x = (t >= off) ? sh[t - off] : 0;
        __syncthreads();
        sh[t] += x;
        __syncthreads();
    }
    if (t < nb) bsum[t] = (t > 0) ? sh[t - 1] : 0;
}

__global__ void k_scan3(const int* __restrict__ spart, const int* __restrict__ bsum,
                        int* __restrict__ rowptr, int N) {
    int i = blockIdx.x * blockDim.x + threadIdx.x;
    if (i < N) rowptr[i + 1] = spart[i] + bsum[i >> 10];
    if (i == 0) rowptr[0] = 0;
}

// Scatter edges into CSR order; also permute edge_attr so agg reads it
// sequentially (kills the eid indirection + random 16B gathers).
__global__ void k_scatter(const int* __restrict__ src, const int* __restrict__ dst,
                          const float4* __restrict__ ea,
                          const int* __restrict__ rowptr, int* __restrict__ fill,
                          int* __restrict__ csr_src, float4* __restrict__ csr_ea, int E) {
    int e = blockIdx.x * blockDim.x + threadIdx.x;
    if (e >= E) return;
    int d = dst[e];
    int pos = rowptr[d] + atomicAdd(&fill[d], 1);
    csr_src[pos] = src[e];
    csr_ea[pos] = ea[e];
}

// Fused GATv2 edge-logits + segment-softmax + aggregation, node-parallel.
// 64 threads (1 wave) per node, 4 nodes per 256-block. Online softmax.
// Thread t owns feature t (head h = t>>4, channel c = t&15).
__global__ void k_gat_agg(const int* __restrict__ rowptr,
                          const int* __restrict__ csr_src,
                          const float4* __restrict__ csr_ea,
                          const float* __restrict__ xl,   // [N,64]
                          const float* __restrict__ xr,   // [N,64]
                          const float* __restrict__ We,   // [4,64]
                          const float* __restrict__ att,  // [64]
                          const float* __restrict__ bias, // [64]
                          float* __restrict__ out,        // [N,64]
                          int N, int elu) {
    int t = threadIdx.x & 63;
    int n = blockIdx.x * 4 + (threadIdx.x >> 6);
    if (n >= N) return;
    float w0 = We[t], w1 = We[64 + t], w2 = We[128 + t], w3 = We[192 + t];
    float av = att[t];
    float xrv = xr[(size_t)n * 64 + t];
    int beg = rowptr[n], end = rowptr[n + 1];
    float m = -INFINITY, denom = 0.f, acc = 0.f;
    for (int j = beg; j < end; ++j) {
        int s = csr_src[j];
        float4 a = csr_ea[j];
        float xlv = xl[(size_t)s * 64 + t];
        float ef = a.x * w0 + a.y * w1 + a.z * w2 + a.w * w3;
        float v = xlv + xrv + ef;
        v = (v >= 0.f) ? v : 0.2f * v;        // LeakyReLU(0.2)
        float pv = v * av;
        // per-head logit: reduce over the 16 channel-lanes
        pv += __shfl_xor(pv, 8, 16);
        pv += __shfl_xor(pv, 4, 16);
        pv += __shfl_xor(pv, 2, 16);
        pv += __shfl_xor(pv, 1, 16);
        float mn = fmaxf(m, pv);
        float scale = expf(m - mn);            // first iter: exp(-inf)=0
        float e = expf(pv - mn);
        denom = denom * scale + e;
        acc = acc * scale + e * xlv;
        m = mn;
    }
    float val = (end > beg) ? (acc / denom) : 0.f;
    val += bias[t];
    if (elu) val = (val > 0.f) ? val : expm1f(val);
    out[(size_t)n * 64 + t] = val;
}

// Run-length accumulating pool: block owns 256 contiguous nodes; thread t owns
// feature t&63, walks nodes with stride 4, flushes one atomicAdd per graph-run.
__global__ void k_pool(const float* __restrict__ y2,
                       const int* __restrict__ batch,
                       float* __restrict__ pool, float* __restrict__ cnt, int N) {
    const int CH = 256;
    int f = threadIdx.x & 63;
    int lane = threadIdx.x >> 6;          // 0..3
    int base = blockIdx.x * CH;
    int curg = -1;
    float acc = 0.f;
    float c = 0.f;
    for (int n = base + lane; n < base + CH && n < N; n += 4) {
        int g = batch[n];
        if (g != curg) {
            if (curg >= 0) {
                atomicAdd(pool + (size_t)curg * 64 + f, acc);
                if (f == 0) atomicAdd(cnt + curg, c);
            }
            curg = g; acc = 0.f; c = 0.f;
        }
        acc += y2[(size_t)n * 64 + f];
        c += 1.f;
    }
    if (curg >= 0) {
        atomicAdd(pool + (size_t)curg * 64 + f, acc);
        if (f == 0) atomicAdd(cnt + curg, c);
    }
}

// One block (64 threads) per graph: mean, 3 MLP heads.
__global__ void k_head(const float* __restrict__ pool, const float* __restrict__ cnt,
                       const float* __restrict__ Wg1, const float* __restrict__ bg1,
                       const float* __restrict__ Wg2, const float* __restrict__ bg2,
                       const float* __restrict__ Wp, const float* __restrict__ bp,
                       const float* __restrict__ Wc1, const float* __restrict__ bc1,
                       const float* __restrict__ Wc2, const float* __restrict__ bc2,
                       float* __restrict__ out) {
    int g = blockIdx.x, f = threadIdx.x;
    __shared__ float sg[64];
    __shared__ float sh[64];
    float inv = 1.f / fmaxf(cnt[g], 1.f);
    sg[f] = pool[(size_t)g * 64 + f] * inv;
    __syncthreads();
    float acc = bg1[f];
    for (int k = 0; k < 64; ++k) acc += sg[k] * Wg1[k * 64 + f];
    sh[f] = fmaxf(acc, 0.f);
    __syncthreads();
    if (f < 15) {
        float o = bg2[f];
        for (int k = 0; k < 64; ++k) o += sh[k] * Wg2[k * 15 + f];
        out[(size_t)g * 15 + f] = o;
    }
    if (f < 10) {
        float o = bp[f];
        for (int k = 0; k < 64; ++k) o += sg[k] * Wp[k * 10 + f];
        out[960 + (size_t)g * 10 + f] = o;
    }
    __syncthreads();
    float acc2 = bc1[f];
    for (int k = 0; k < 64; ++k) acc2 += sg[k] * Wc1[k * 64 + f];
    sh[f] = fmaxf(acc2, 0.f);
    __syncthreads();
    if (f == 0) {
        float v = bc2[0];
        for (int k = 0; k < 64; ++k) v += sh[k] * Wc2[k];
        out[1600 + g] = v;
    }
}

extern "C" void kernel_launch(void* const* d_in, const int* in_sizes, int n_in,
                              void* d_out, int out_size, void* d_ws, size_t ws_size,
                              hipStream_t stream) {
    const float* x     = (const float*)d_in[0];
    const int*   ei    = (const int*)d_in[1];
    const float* ea    = (const float*)d_in[2];
    const int*   batch = (const int*)d_in[3];
    const float* Wl1 = (const float*)d_in[4];
    const float* Wr1 = (const float*)d_in[5];
    const float* We1 = (const float*)d_in[6];
    const float* att1 = (const float*)d_in[7];
    const float* b1  = (const float*)d_in[8];
    const float* Wl2 = (const float*)d_in[9];
    const float* Wr2 = (const float*)d_in[10];
    const float* We2 = (const float*)d_in[11];
    const float* att2 = (const float*)d_in[12];
    const float* b2  = (const float*)d_in[13];
    const float* Wg1 = (const float*)d_in[14];
    const float* bg1 = (const float*)d_in[15];
    const float* Wg2 = (const float*)d_in[16];
    const float* bg2 = (const float*)d_in[17];
    const float* Wp  = (const float*)d_in[18];
    const float* bp  = (const float*)d_in[19];
    const float* Wc1 = (const float*)d_in[20];
    const float* bc1 = (const float*)d_in[21];
    const float* Wc2 = (const float*)d_in[22];
    const float* bc2 = (const float*)d_in[23];

    const int N = in_sizes[0] / 16;       // 100000
    const int E = in_sizes[2] / 4;        // 1600000
    const int* src = ei;
    const int* dst = ei + E;

    // workspace layout (floats)
    float* ws = (float*)d_ws;
    size_t NF = (size_t)N * 64;
    float* A  = ws;                       // xl1, later xr2
    float* B  = A + NF;                   // xr1, later xl2
    float* C  = B + NF;                   // y1, later y2
    float4* csr_ea = (float4*)(C + NF);   // [E] permuted edge_attr (16B aligned)
    int* csr_src = (int*)(csr_ea + E);    // [E]
    int* rowptr  = csr_src + E;           // N+1
    int* deg     = rowptr + (N + 1);      // N (reused as fill)
    int* spart   = deg + N;               // N
    int* bsum    = spart + N;             // 128
    float* PL    = (float*)(bsum + 128);  // [64,64]
    float* CT    = PL + 64 * 64;          // [64]

    dim3 blk(256);
    int gNF = (int)((NF + 255) / 256);
    int gE  = (E + 255) / 256;
    int gN  = (N + 255) / 256;
    int nb1 = (N + 1023) / 1024;
    int gAgg = (N + 3) / 4;

    // ---- CSR build (shared by both layers) ----
    hipMemsetAsync(deg, 0, (size_t)N * sizeof(int), stream);
    k_deg<<<gE, blk, 0, stream>>>(dst, deg, E);
    k_scan1<<<nb1, blk, 0, stream>>>(deg, spart, bsum, N);
    k_scan2<<<1, 128, 0, stream>>>(bsum, nb1);
    k_scan3<<<gN, blk, 0, stream>>>(spart, bsum, rowptr, N);
    hipMemsetAsync(deg, 0, (size_t)N * sizeof(int), stream);  // reuse as fill
    k_scatter<<<gE, blk, 0, stream>>>(src, dst, (const float4*)ea, rowptr, deg,
                                      csr_src, csr_ea, E);

    // ---- Layer 1 ----
    k_node_lin2<<<gNF, blk, 0, stream>>>(x, Wl1, Wr1, A, B, N, 16, 64);
    k_gat_agg<<<gAgg, blk, 0, stream>>>(rowptr, csr_src, csr_ea, A, B, We1, att1,
                                        b1, C, N, 1);

    // ---- Layer 2 ---- (xl2 -> B, xr2 -> A)
    k_node_lin2<<<gNF, blk, 0, stream>>>(C, Wl2, Wr2, B, A, N, 64, 64);
    k_gat_agg<<<gAgg, blk, 0, stream>>>(rowptr, csr_src, csr_ea, B, A, We2, att2,
                                        b2, C, N, 0);

    // ---- Pool + heads ----
    hipMemsetAsync(PL, 0, (64 * 64 + 64) * sizeof(float), stream);
    k_pool<<<(N + 255) / 256, blk, 0, stream>>>(C, batch, PL, CT, N);
    k_head<<<64, 64, 0, stream>>>(PL, CT, Wg1, bg1, Wg2, bg2, Wp, bp,
                                  Wc1, bc1, Wc2, bc2, (float*)d_out);
}

// Round 5
// 703.188 us; speedup vs baseline: 18.7915x; 1.2016x over previous
//
#include <hip/hip_runtime.h>

#define DEVINL __device__ __forceinline__

// x[N,K] @ Wa[K,F] -> oa[N,F]; same x @ Wb -> ob. Thread per (n,f).
__global__ void k_node_lin2(const float* __restrict__ x,
                            const float* __restrict__ Wa,
                            const float* __restrict__ Wb,
                            float* __restrict__ oa, float* __restrict__ ob,
                            int N, int K, int F) {
    int idx = blockIdx.x * blockDim.x + threadIdx.x;
    if (idx >= N * F) return;
    int n = idx / F, f = idx % F;
    const float* xrow = x + (size_t)n * K;
    float aa = 0.f, ab = 0.f;
    for (int k = 0; k < K; ++k) {
        float xv = xrow[k];
        aa += xv * Wa[k * F + f];
        ab += xv * Wb[k * F + f];
    }
    oa[idx] = aa;
    ob[idx] = ab;
}

// ---- CSR build ----
__global__ void k_deg(const int* __restrict__ dst, int* __restrict__ deg, int E) {
    int e = blockIdx.x * blockDim.x + threadIdx.x;
    if (e < E) atomicAdd(&deg[dst[e]], 1);
}

__global__ void k_scan1(const int* __restrict__ deg, int* __restrict__ spart,
                        int* __restrict__ bsum, int N) {
    __shared__ int sh[256];
    int base = blockIdx.x * 1024;
    int t = threadIdx.x;
    int v[4]; int sum = 0;
#pragma unroll
    for (int i = 0; i < 4; ++i) {
        int idx = base + t * 4 + i;
        v[i] = (idx < N) ? deg[idx] : 0;
        sum += v[i];
    }
    sh[t] = sum;
    __syncthreads();
    for (int off = 1; off < 256; off <<= 1) {
        int x = (t >= off) ? sh[t - off] : 0;
        __syncthreads();
        sh[t] += x;
        __syncthreads();
    }
    int run = (t > 0) ? sh[t - 1] : 0;
#pragma unroll
    for (int i = 0; i < 4; ++i) {
        run += v[i];
        int idx = base + t * 4 + i;
        if (idx < N) spart[idx] = run;
    }
    if (t == 255) bsum[blockIdx.x] = sh[255];
}

__global__ void k_scan2(int* __restrict__ bsum, int nb) {
    __shared__ int sh[128];
    int t = threadIdx.x;
    sh[t] = (t < nb) ? bsum[t] : 0;
    __syncthreads();
    for (int off = 1; off < 128; off <<= 1) {
        int x = (t >= off) ? sh[t - off] : 0;
        __syncthreads();
        sh[t] += x;
        __syncthreads();
    }
    if (t < nb) bsum[t] = (t > 0) ? sh[t - 1] : 0;
}

__global__ void k_scan3(const int* __restrict__ spart, const int* __restrict__ bsum,
                        int* __restrict__ rowptr, int N) {
    int i = blockIdx.x * blockDim.x + threadIdx.x;
    if (i < N) rowptr[i + 1] = spart[i] + bsum[i >> 10];
    if (i == 0) rowptr[0] = 0;
}

// Scatter edges into CSR order; permute edge_attr along for sequential reads.
__global__ void k_scatter(const int* __restrict__ src, const int* __restrict__ dst,
                          const float4* __restrict__ ea,
                          const int* __restrict__ rowptr, int* __restrict__ fill,
                          int* __restrict__ csr_src, float4* __restrict__ csr_ea, int E) {
    int e = blockIdx.x * blockDim.x + threadIdx.x;
    if (e >= E) return;
    int d = dst[e];
    int pos = rowptr[d] + atomicAdd(&fill[d], 1);
    csr_src[pos] = src[e];
    csr_ea[pos] = ea[e];
}

// Per-edge logit (log2 domain) + gather of this thread's xl feature.
DEVINL float edge_logit(int s, float4 a, float xrv,
                        float w0, float w1, float w2, float w3, float av2,
                        const float* __restrict__ xl, int t, float& xlv) {
    xlv = xl[(size_t)s * 64 + t];
    float ef = fmaf(a.x, w0, fmaf(a.y, w1, fmaf(a.z, w2, a.w * w3)));
    float v = xlv + xrv + ef;
    v = (v >= 0.f) ? v : 0.2f * v;          // LeakyReLU(0.2)
    float pv = v * av2;                      // att * log2(e) folded in
    pv += __shfl_xor(pv, 8, 16);
    pv += __shfl_xor(pv, 4, 16);
    pv += __shfl_xor(pv, 2, 16);
    pv += __shfl_xor(pv, 1, 16);
    return pv;                               // per-head logit, log2 domain
}

// Fused GATv2 logits + segment-softmax + aggregation, node-parallel.
// 64 threads (1 wave) per node, 4 nodes per 256-block.
// Deferred-max softmax in log2 domain, edge loop unrolled x2.
__global__ void k_gat_agg(const int* __restrict__ rowptr,
                          const int* __restrict__ csr_src,
                          const float4* __restrict__ csr_ea,
                          const float* __restrict__ xl,   // [N,64]
                          const float* __restrict__ xr,   // [N,64]
                          const float* __restrict__ We,   // [4,64]
                          const float* __restrict__ att,  // [64]
                          const float* __restrict__ bias, // [64]
                          float* __restrict__ out,        // [N,64]
                          int N, int elu) {
    int t = threadIdx.x & 63;
    int n = blockIdx.x * 4 + (threadIdx.x >> 6);
    if (n >= N) return;
    float w0 = We[t], w1 = We[64 + t], w2 = We[128 + t], w3 = We[192 + t];
    float av2 = att[t] * 1.44269504088896f;   // log2(e)
    float xrv = xr[(size_t)n * 64 + t];
    int beg = rowptr[n], end = rowptr[n + 1];

    float val;
    if (beg == end) {
        val = 0.f;
    } else {
        // peel first edge: e = exp2(pv-pv) = 1
        float xlv0;
        float m = edge_logit(csr_src[beg], csr_ea[beg], xrv, w0, w1, w2, w3, av2, xl, t, xlv0);
        float denom = 1.f, acc = xlv0;
        int j = beg + 1;
        for (; j + 1 < end; j += 2) {
            int s0 = csr_src[j], s1 = csr_src[j + 1];
            float4 a0 = csr_ea[j], a1 = csr_ea[j + 1];
            float x0, x1;
            float p0 = edge_logit(s0, a0, xrv, w0, w1, w2, w3, av2, xl, t, x0);
            float p1 = edge_logit(s1, a1, xrv, w0, w1, w2, w3, av2, xl, t, x1);
            if (__any(fmaxf(p0, p1) - m > 8.f)) {      // rare rescale path
                float mn = fmaxf(m, fmaxf(p0, p1));
                float sc = exp2f(m - mn);
                float e0 = exp2f(p0 - mn), e1 = exp2f(p1 - mn);
                denom = denom * sc + e0 + e1;
                acc = fmaf(acc, sc, fmaf(e0, x0, e1 * x1));
                m = mn;
            } else {                                    // fast path: 2 exp2
                float e0 = exp2f(p0 - m), e1 = exp2f(p1 - m);
                denom += e0 + e1;
                acc = fmaf(e0, x0, fmaf(e1, x1, acc));
            }
        }
        if (j < end) {                                  // tail edge
            float x0;
            float p0 = edge_logit(csr_src[j], csr_ea[j], xrv, w0, w1, w2, w3, av2, xl, t, x0);
            if (__any(p0 - m > 8.f)) {
                float mn = fmaxf(m, p0);
                float sc = exp2f(m - mn);
                float e0 = exp2f(p0 - mn);
                denom = denom * sc + e0;
                acc = fmaf(acc, sc, e0 * x0);
                m = mn;
            } else {
                float e0 = exp2f(p0 - m);
                denom += e0;
                acc = fmaf(e0, x0, acc);
            }
        }
        val = acc / denom;   // denom >= 2^-8 always (m only grows on trigger)
    }
    val += bias[t];
    if (elu) val = (val > 0.f) ? val : expm1f(val);
    out[(size_t)n * 64 + t] = val;
}

// Run-length accumulating pool: block owns 256 contiguous nodes; thread t owns
// feature t&63, walks nodes with stride 4, flushes one atomicAdd per graph-run.
__global__ void k_pool(const float* __restrict__ y2,
                       const int* __restrict__ batch,
                       float* __restrict__ pool, float* __restrict__ cnt, int N) {
    const int CH = 256;
    int f = threadIdx.x & 63;
    int lane = threadIdx.x >> 6;          // 0..3
    int base = blockIdx.x * CH;
    int curg = -1;
    float acc = 0.f;
    float c = 0.f;
    for (int n = base + lane; n < base + CH && n < N; n += 4) {
        int g = batch[n];
        if (g != curg) {
            if (curg >= 0) {
                atomicAdd(pool + (size_t)curg * 64 + f, acc);
                if (f == 0) atomicAdd(cnt + curg, c);
            }
            curg = g; acc = 0.f; c = 0.f;
        }
        acc += y2[(size_t)n * 64 + f];
        c += 1.f;
    }
    if (curg >= 0) {
        atomicAdd(pool + (size_t)curg * 64 + f, acc);
        if (f == 0) atomicAdd(cnt + curg, c);
    }
}

// One block (64 threads) per graph: mean, 3 MLP heads.
__global__ void k_head(const float* __restrict__ pool, const float* __restrict__ cnt,
                       const float* __restrict__ Wg1, const float* __restrict__ bg1,
                       const float* __restrict__ Wg2, const float* __restrict__ bg2,
                       const float* __restrict__ Wp, const float* __restrict__ bp,
                       const float* __restrict__ Wc1, const float* __restrict__ bc1,
                       const float* __restrict__ Wc2, const float* __restrict__ bc2,
                       float* __restrict__ out) {
    int g = blockIdx.x, f = threadIdx.x;
    __shared__ float sg[64];
    __shared__ float sh[64];
    float inv = 1.f / fmaxf(cnt[g], 1.f);
    sg[f] = pool[(size_t)g * 64 + f] * inv;
    __syncthreads();
    float acc = bg1[f];
    for (int k = 0; k < 64; ++k) acc += sg[k] * Wg1[k * 64 + f];
    sh[f] = fmaxf(acc, 0.f);
    __syncthreads();
    if (f < 15) {
        float o = bg2[f];
        for (int k = 0; k < 64; ++k) o += sh[k] * Wg2[k * 15 + f];
        out[(size_t)g * 15 + f] = o;
    }
    if (f < 10) {
        float o = bp[f];
        for (int k = 0; k < 64; ++k) o += sg[k] * Wp[k * 10 + f];
        out[960 + (size_t)g * 10 + f] = o;
    }
    __syncthreads();
    float acc2 = bc1[f];
    for (int k = 0; k < 64; ++k) acc2 += sg[k] * Wc1[k * 64 + f];
    sh[f] = fmaxf(acc2, 0.f);
    __syncthreads();
    if (f == 0) {
        float v = bc2[0];
        for (int k = 0; k < 64; ++k) v += sh[k] * Wc2[k];
        out[1600 + g] = v;
    }
}

extern "C" void kernel_launch(void* const* d_in, const int* in_sizes, int n_in,
                              void* d_out, int out_size, void* d_ws, size_t ws_size,
                              hipStream_t stream) {
    const float* x     = (const float*)d_in[0];
    const int*   ei    = (const int*)d_in[1];
    const float* ea    = (const float*)d_in[2];
    const int*   batch = (const int*)d_in[3];
    const float* Wl1 = (const float*)d_in[4];
    const float* Wr1 = (const float*)d_in[5];
    const float* We1 = (const float*)d_in[6];
    const float* att1 = (const float*)d_in[7];
    const float* b1  = (const float*)d_in[8];
    const float* Wl2 = (const float*)d_in[9];
    const float* Wr2 = (const float*)d_in[10];
    const float* We2 = (const float*)d_in[11];
    const float* att2 = (const float*)d_in[12];
    const float* b2  = (const float*)d_in[13];
    const float* Wg1 = (const float*)d_in[14];
    const float* bg1 = (const float*)d_in[15];
    const float* Wg2 = (const float*)d_in[16];
    const float* bg2 = (const float*)d_in[17];
    const float* Wp  = (const float*)d_in[18];
    const float* bp  = (const float*)d_in[19];
    const float* Wc1 = (const float*)d_in[20];
    const float* bc1 = (const float*)d_in[21];
    const float* Wc2 = (const float*)d_in[22];
    const float* bc2 = (const float*)d_in[23];

    const int N = in_sizes[0] / 16;       // 100000
    const int E = in_sizes[2] / 4;        // 1600000
    const int* src = ei;
    const int* dst = ei + E;

    // workspace layout (floats)
    float* ws = (float*)d_ws;
    size_t NF = (size_t)N * 64;
    float* A  = ws;                       // xl1, later xr2
    float* B  = A + NF;                   // xr1, later xl2
    float* C  = B + NF;                   // y1, later y2
    float4* csr_ea = (float4*)(C + NF);   // [E] permuted edge_attr (16B aligned)
    int* csr_src = (int*)(csr_ea + E);    // [E]
    int* rowptr  = csr_src + E;           // N+1
    int* deg     = rowptr + (N + 1);      // N (reused as fill)
    int* spart   = deg + N;               // N
    int* bsum    = spart + N;             // 128
    float* PL    = (float*)(bsum + 128);  // [64,64]
    float* CT    = PL + 64 * 64;          // [64]

    dim3 blk(256);
    int gNF = (int)((NF + 255) / 256);
    int gE  = (E + 255) / 256;
    int gN  = (N + 255) / 256;
    int nb1 = (N + 1023) / 1024;
    int gAgg = (N + 3) / 4;

    // ---- CSR build (shared by both layers) ----
    hipMemsetAsync(deg, 0, (size_t)N * sizeof(int), stream);
    k_deg<<<gE, blk, 0, stream>>>(dst, deg, E);
    k_scan1<<<nb1, blk, 0, stream>>>(deg, spart, bsum, N);
    k_scan2<<<1, 128, 0, stream>>>(bsum, nb1);
    k_scan3<<<gN, blk, 0, stream>>>(spart, bsum, rowptr, N);
    hipMemsetAsync(deg, 0, (size_t)N * sizeof(int), stream);  // reuse as fill
    k_scatter<<<gE, blk, 0, stream>>>(src, dst, (const float4*)ea, rowptr, deg,
                                      csr_src, csr_ea, E);

    // ---- Layer 1 ----
    k_node_lin2<<<gNF, blk, 0, stream>>>(x, Wl1, Wr1, A, B, N, 16, 64);
    k_gat_agg<<<gAgg, blk, 0, stream>>>(rowptr, csr_src, csr_ea, A, B, We1, att1,
                                        b1, C, N, 1);

    // ---- Layer 2 ---- (xl2 -> B, xr2 -> A)
    k_node_lin2<<<gNF, blk, 0, stream>>>(C, Wl2, Wr2, B, A, N, 64, 64);
    k_gat_agg<<<gAgg, blk, 0, stream>>>(rowptr, csr_src, csr_ea, B, A, We2, att2,
                                        b2, C, N, 0);

    // ---- Pool + heads ----
    hipMemsetAsync(PL, 0, (64 * 64 + 64) * sizeof(float), stream);
    k_pool<<<(N + 255) / 256, blk, 0, stream>>>(C, batch, PL, CT, N);
    k_head<<<64, 64, 0, stream>>>(PL, CT, Wg1, bg1, Wg2, bg2, Wp, bp,
                                  Wc1, bc1, Wc2, bc2, (float*)d_out);
}

// Round 6
// 563.729 us; speedup vs baseline: 23.4403x; 1.2474x over previous
//
#include <hip/hip_runtime.h>

#define DEVINL __device__ __forceinline__

// LDS-tiled GEMM: out[n, 0:128] = x[n, 0:K] @ [Wa | Wb], split back into
// oa[n,0:64], ob[n,0:64]. Block = 256 threads -> 64-node x 128-col tile.
// Thread owns 8 nodes x 4 cols = 32 accumulators.
template <int K>
__global__ void k_lin_tiled(const float* __restrict__ x,
                            const float* __restrict__ Wa,
                            const float* __restrict__ Wb,
                            float* __restrict__ oa, float* __restrict__ ob,
                            int N) {
    __shared__ float sx[64 * K];     // x tile, row-major [64][K]
    __shared__ float sw[K * 128];    // [K][128] = [K][Wa|Wb]
    int t = threadIdx.x;
    int base = blockIdx.x * 64;

    // stage W (both matrices), coalesced float4
    const int WTOT = K * 64 / 4;     // float4s per matrix
    for (int i = t; i < WTOT; i += 256) {
        float4 wa = ((const float4*)Wa)[i];
        float4 wb = ((const float4*)Wb)[i];
        int k = (i * 4) >> 6, f = (i * 4) & 63;
        *(float4*)&sw[k * 128 + f] = wa;
        *(float4*)&sw[k * 128 + 64 + f] = wb;
    }
    // stage x tile, coalesced float4, no transpose
    const int XTOT = 64 * K / 4;
    for (int i = t; i < XTOT; i += 256) {
        int n = (i * 4) / K, kk = (i * 4) % K;
        float4 v = make_float4(0.f, 0.f, 0.f, 0.f);
        if (base + n < N) v = *(const float4*)&x[(size_t)(base + n) * K + kk];
        *(float4*)&sx[n * K + kk] = v;
    }
    __syncthreads();

    int fq = t & 31;    // col group: cols fq*4 .. fq*4+3 of [Wa|Wb]
    int nq = t >> 5;    // node group: nodes nq*8 .. nq*8+7
    float acc[8][4];
#pragma unroll
    for (int i = 0; i < 8; ++i)
#pragma unroll
        for (int c = 0; c < 4; ++c) acc[i][c] = 0.f;

    for (int k0 = 0; k0 < K; k0 += 4) {
        float4 xv[8];
#pragma unroll
        for (int i = 0; i < 8; ++i)
            xv[i] = *(const float4*)&sx[(nq * 8 + i) * K + k0];
#pragma unroll
        for (int kk = 0; kk < 4; ++kk) {
            float4 w = *(const float4*)&sw[(k0 + kk) * 128 + fq * 4];
#pragma unroll
            for (int i = 0; i < 8; ++i) {
                float xs = (kk == 0) ? xv[i].x : (kk == 1) ? xv[i].y
                         : (kk == 2) ? xv[i].z : xv[i].w;
                acc[i][0] = fmaf(xs, w.x, acc[i][0]);
                acc[i][1] = fmaf(xs, w.y, acc[i][1]);
                acc[i][2] = fmaf(xs, w.z, acc[i][2]);
                acc[i][3] = fmaf(xs, w.w, acc[i][3]);
            }
        }
    }

    int col = fq * 4;
    float* o = (col < 64) ? oa : ob;
    int c = col & 63;
#pragma unroll
    for (int i = 0; i < 8; ++i) {
        int n = base + nq * 8 + i;
        if (n < N)
            *(float4*)&o[(size_t)n * 64 + c] =
                make_float4(acc[i][0], acc[i][1], acc[i][2], acc[i][3]);
    }
}

// ---- CSR build ----
__global__ void k_deg(const int* __restrict__ dst, int* __restrict__ deg, int E) {
    int e = blockIdx.x * blockDim.x + threadIdx.x;
    if (e < E) atomicAdd(&deg[dst[e]], 1);
}

__global__ void k_scan1(const int* __restrict__ deg, int* __restrict__ spart,
                        int* __restrict__ bsum, int N) {
    __shared__ int sh[256];
    int base = blockIdx.x * 1024;
    int t = threadIdx.x;
    int v[4]; int sum = 0;
#pragma unroll
    for (int i = 0; i < 4; ++i) {
        int idx = base + t * 4 + i;
        v[i] = (idx < N) ? deg[idx] : 0;
        sum += v[i];
    }
    sh[t] = sum;
    __syncthreads();
    for (int off = 1; off < 256; off <<= 1) {
        int x = (t >= off) ? sh[t - off] : 0;
        __syncthreads();
        sh[t] += x;
        __syncthreads();
    }
    int run = (t > 0) ? sh[t - 1] : 0;
#pragma unroll
    for (int i = 0; i < 4; ++i) {
        run += v[i];
        int idx = base + t * 4 + i;
        if (idx < N) spart[idx] = run;
    }
    if (t == 255) bsum[blockIdx.x] = sh[255];
}

__global__ void k_scan2(int* __restrict__ bsum, int nb) {
    __shared__ int sh[128];
    int t = threadIdx.x;
    sh[t] = (t < nb) ? bsum[t] : 0;
    __syncthreads();
    for (int off = 1; off < 128; off <<= 1) {
        int x = (t >= off) ? sh[t - off] : 0;
        __syncthreads();
        sh[t] += x;
        __syncthreads();
    }
    if (t < nb) bsum[t] = (t > 0) ? sh[t - 1] : 0;
}

__global__ void k_scan3(const int* __restrict__ spart, const int* __restrict__ bsum,
                        int* __restrict__ rowptr, int N) {
    int i = blockIdx.x * blockDim.x + threadIdx.x;
    if (i < N) rowptr[i + 1] = spart[i] + bsum[i >> 10];
    if (i == 0) rowptr[0] = 0;
}

// Scatter edges into CSR order; permute edge_attr along for sequential reads.
__global__ void k_scatter(const int* __restrict__ src, const int* __restrict__ dst,
                          const float4* __restrict__ ea,
                          const int* __restrict__ rowptr, int* __restrict__ fill,
                          int* __restrict__ csr_src, float4* __restrict__ csr_ea, int E) {
    int e = blockIdx.x * blockDim.x + threadIdx.x;
    if (e >= E) return;
    int d = dst[e];
    int pos = rowptr[d] + atomicAdd(&fill[d], 1);
    csr_src[pos] = src[e];
    csr_ea[pos] = ea[e];
}

// Per-edge logit (log2 domain) + gather of this thread's xl feature.
DEVINL float edge_logit(int s, float4 a, float xrv,
                        float w0, float w1, float w2, float w3, float av2,
                        const float* __restrict__ xl, int t, float& xlv) {
    xlv = xl[(size_t)s * 64 + t];
    float ef = fmaf(a.x, w0, fmaf(a.y, w1, fmaf(a.z, w2, a.w * w3)));
    float v = xlv + xrv + ef;
    v = (v >= 0.f) ? v : 0.2f * v;          // LeakyReLU(0.2)
    float pv = v * av2;                      // att * log2(e) folded in
    pv += __shfl_xor(pv, 8, 16);
    pv += __shfl_xor(pv, 4, 16);
    pv += __shfl_xor(pv, 2, 16);
    pv += __shfl_xor(pv, 1, 16);
    return pv;                               // per-head logit, log2 domain
}

// Fused GATv2 logits + segment-softmax + aggregation, node-parallel.
__global__ void k_gat_agg(const int* __restrict__ rowptr,
                          const int* __restrict__ csr_src,
                          const float4* __restrict__ csr_ea,
                          const float* __restrict__ xl,   // [N,64]
                          const float* __restrict__ xr,   // [N,64]
                          const float* __restrict__ We,   // [4,64]
                          const float* __restrict__ att,  // [64]
                          const float* __restrict__ bias, // [64]
                          float* __restrict__ out,        // [N,64]
                          int N, int elu) {
    int t = threadIdx.x & 63;
    int n = blockIdx.x * 4 + (threadIdx.x >> 6);
    if (n >= N) return;
    float w0 = We[t], w1 = We[64 + t], w2 = We[128 + t], w3 = We[192 + t];
    float av2 = att[t] * 1.44269504088896f;   // log2(e)
    float xrv = xr[(size_t)n * 64 + t];
    int beg = rowptr[n], end = rowptr[n + 1];

    float val;
    if (beg == end) {
        val = 0.f;
    } else {
        float xlv0;
        float m = edge_logit(csr_src[beg], csr_ea[beg], xrv, w0, w1, w2, w3, av2, xl, t, xlv0);
        float denom = 1.f, acc = xlv0;
        int j = beg + 1;
        for (; j + 1 < end; j += 2) {
            int s0 = csr_src[j], s1 = csr_src[j + 1];
            float4 a0 = csr_ea[j], a1 = csr_ea[j + 1];
            float x0, x1;
            float p0 = edge_logit(s0, a0, xrv, w0, w1, w2, w3, av2, xl, t, x0);
            float p1 = edge_logit(s1, a1, xrv, w0, w1, w2, w3, av2, xl, t, x1);
            if (__any(fmaxf(p0, p1) - m > 8.f)) {
                float mn = fmaxf(m, fmaxf(p0, p1));
                float sc = exp2f(m - mn);
                float e0 = exp2f(p0 - mn), e1 = exp2f(p1 - mn);
                denom = denom * sc + e0 + e1;
                acc = fmaf(acc, sc, fmaf(e0, x0, e1 * x1));
                m = mn;
            } else {
                float e0 = exp2f(p0 - m), e1 = exp2f(p1 - m);
                denom += e0 + e1;
                acc = fmaf(e0, x0, fmaf(e1, x1, acc));
            }
        }
        if (j < end) {
            float x0;
            float p0 = edge_logit(csr_src[j], csr_ea[j], xrv, w0, w1, w2, w3, av2, xl, t, x0);
            if (__any(p0 - m > 8.f)) {
                float mn = fmaxf(m, p0);
                float sc = exp2f(m - mn);
                float e0 = exp2f(p0 - mn);
                denom = denom * sc + e0;
                acc = fmaf(acc, sc, e0 * x0);
                m = mn;
            } else {
                float e0 = exp2f(p0 - m);
                denom += e0;
                acc = fmaf(e0, x0, acc);
            }
        }
        val = acc / denom;
    }
    val += bias[t];
    if (elu) val = (val > 0.f) ? val : expm1f(val);
    out[(size_t)n * 64 + t] = val;
}

// Run-length accumulating pool.
__global__ void k_pool(const float* __restrict__ y2,
                       const int* __restrict__ batch,
                       float* __restrict__ pool, float* __restrict__ cnt, int N) {
    const int CH = 256;
    int f = threadIdx.x & 63;
    int lane = threadIdx.x >> 6;          // 0..3
    int base = blockIdx.x * CH;
    int curg = -1;
    float acc = 0.f;
    float c = 0.f;
    for (int n = base + lane; n < base + CH && n < N; n += 4) {
        int g = batch[n];
        if (g != curg) {
            if (curg >= 0) {
                atomicAdd(pool + (size_t)curg * 64 + f, acc);
                if (f == 0) atomicAdd(cnt + curg, c);
            }
            curg = g; acc = 0.f; c = 0.f;
        }
        acc += y2[(size_t)n * 64 + f];
        c += 1.f;
    }
    if (curg >= 0) {
        atomicAdd(pool + (size_t)curg * 64 + f, acc);
        if (f == 0) atomicAdd(cnt + curg, c);
    }
}

// One block (64 threads) per graph: mean, 3 MLP heads.
__global__ void k_head(const float* __restrict__ pool, const float* __restrict__ cnt,
                       const float* __restrict__ Wg1, const float* __restrict__ bg1,
                       const float* __restrict__ Wg2, const float* __restrict__ bg2,
                       const float* __restrict__ Wp, const float* __restrict__ bp,
                       const float* __restrict__ Wc1, const float* __restrict__ bc1,
                       const float* __restrict__ Wc2, const float* __restrict__ bc2,
                       float* __restrict__ out) {
    int g = blockIdx.x, f = threadIdx.x;
    __shared__ float sg[64];
    __shared__ float sh[64];
    float inv = 1.f / fmaxf(cnt[g], 1.f);
    sg[f] = pool[(size_t)g * 64 + f] * inv;
    __syncthreads();
    float acc = bg1[f];
    for (int k = 0; k < 64; ++k) acc += sg[k] * Wg1[k * 64 + f];
    sh[f] = fmaxf(acc, 0.f);
    __syncthreads();
    if (f < 15) {
        float o = bg2[f];
        for (int k = 0; k < 64; ++k) o += sh[k] * Wg2[k * 15 + f];
        out[(size_t)g * 15 + f] = o;
    }
    if (f < 10) {
        float o = bp[f];
        for (int k = 0; k < 64; ++k) o += sg[k] * Wp[k * 10 + f];
        out[960 + (size_t)g * 10 + f] = o;
    }
    __syncthreads();
    float acc2 = bc1[f];
    for (int k = 0; k < 64; ++k) acc2 += sg[k] * Wc1[k * 64 + f];
    sh[f] = fmaxf(acc2, 0.f);
    __syncthreads();
    if (f == 0) {
        float v = bc2[0];
        for (int k = 0; k < 64; ++k) v += sh[k] * Wc2[k];
        out[1600 + g] = v;
    }
}

extern "C" void kernel_launch(void* const* d_in, const int* in_sizes, int n_in,
                              void* d_out, int out_size, void* d_ws, size_t ws_size,
                              hipStream_t stream) {
    const float* x     = (const float*)d_in[0];
    const int*   ei    = (const int*)d_in[1];
    const float* ea    = (const float*)d_in[2];
    const int*   batch = (const int*)d_in[3];
    const float* Wl1 = (const float*)d_in[4];
    const float* Wr1 = (const float*)d_in[5];
    const float* We1 = (const float*)d_in[6];
    const float* att1 = (const float*)d_in[7];
    const float* b1  = (const float*)d_in[8];
    const float* Wl2 = (const float*)d_in[9];
    const float* Wr2 = (const float*)d_in[10];
    const float* We2 = (const float*)d_in[11];
    const float* att2 = (const float*)d_in[12];
    const float* b2  = (const float*)d_in[13];
    const float* Wg1 = (const float*)d_in[14];
    const float* bg1 = (const float*)d_in[15];
    const float* Wg2 = (const float*)d_in[16];
    const float* bg2 = (const float*)d_in[17];
    const float* Wp  = (const float*)d_in[18];
    const float* bp  = (const float*)d_in[19];
    const float* Wc1 = (const float*)d_in[20];
    const float* bc1 = (const float*)d_in[21];
    const float* Wc2 = (const float*)d_in[22];
    const float* bc2 = (const float*)d_in[23];

    const int N = in_sizes[0] / 16;       // 100000
    const int E = in_sizes[2] / 4;        // 1600000
    const int* src = ei;
    const int* dst = ei + E;

    // workspace layout (floats)
    float* ws = (float*)d_ws;
    size_t NF = (size_t)N * 64;
    float* A  = ws;                       // xl1, later xr2
    float* B  = A + NF;                   // xr1, later xl2
    float* C  = B + NF;                   // y1, later y2
    float4* csr_ea = (float4*)(C + NF);   // [E] permuted edge_attr
    int* csr_src = (int*)(csr_ea + E);    // [E]
    int* rowptr  = csr_src + E;           // N+1
    int* deg     = rowptr + (N + 1);      // N (reused as fill)
    int* spart   = deg + N;               // N
    int* bsum    = spart + N;             // 128
    float* PL    = (float*)(bsum + 128);  // [64,64]
    float* CT    = PL + 64 * 64;          // [64]

    dim3 blk(256);
    int gE  = (E + 255) / 256;
    int gN  = (N + 255) / 256;
    int nb1 = (N + 1023) / 1024;
    int gAgg = (N + 3) / 4;
    int gLin = (N + 63) / 64;

    // ---- CSR build (shared by both layers) ----
    hipMemsetAsync(deg, 0, (size_t)N * sizeof(int), stream);
    k_deg<<<gE, blk, 0, stream>>>(dst, deg, E);
    k_scan1<<<nb1, blk, 0, stream>>>(deg, spart, bsum, N);
    k_scan2<<<1, 128, 0, stream>>>(bsum, nb1);
    k_scan3<<<gN, blk, 0, stream>>>(spart, bsum, rowptr, N);
    hipMemsetAsync(deg, 0, (size_t)N * sizeof(int), stream);  // reuse as fill
    k_scatter<<<gE, blk, 0, stream>>>(src, dst, (const float4*)ea, rowptr, deg,
                                      csr_src, csr_ea, E);

    // ---- Layer 1 ----
    k_lin_tiled<16><<<gLin, blk, 0, stream>>>(x, Wl1, Wr1, A, B, N);
    k_gat_agg<<<gAgg, blk, 0, stream>>>(rowptr, csr_src, csr_ea, A, B, We1, att1,
                                        b1, C, N, 1);

    // ---- Layer 2 ---- (xl2 -> B, xr2 -> A)
    k_lin_tiled<64><<<gLin, blk, 0, stream>>>(C, Wl2, Wr2, B, A, N);
    k_gat_agg<<<gAgg, blk, 0, stream>>>(rowptr, csr_src, csr_ea, B, A, We2, att2,
                                        b2, C, N, 0);

    // ---- Pool + heads ----
    hipMemsetAsync(PL, 0, (64 * 64 + 64) * sizeof(float), stream);
    k_pool<<<(N + 255) / 256, blk, 0, stream>>>(C, batch, PL, CT, N);
    k_head<<<64, 64, 0, stream>>>(PL, CT, Wg1, bg1, Wg2, bg2, Wp, bp,
                                  Wc1, bc1, Wc2, bc2, (float*)d_out);
}